// Round 10
// baseline (881.407 us; speedup 1.0000x reference)
//
#include <hip/hip_runtime.h>
#include <math.h>

// Problem constants: D=2048, E=8, T=32768, top_k=2
constexpr int D_DIM  = 2048;
constexpr int NEXP   = 8;
constexpr int NTOK   = 32768;
constexpr int TT     = 2;              // tokens per wave per group
constexpr int SR     = 256;            // k-rows per super (1 KiB of a token row)
constexpr int NS     = D_DIM / SR;     // 8 supers
constexpr int WAVES  = 16;             // waves per block
constexpr int BLKT   = WAVES * 64;     // 1024 threads
constexpr int NBLK   = 256;            // 1 block per CU
constexpr int GROUPS = NTOK / (NBLK * WAVES * TT);   // 4 groups per wave

typedef float vf4 __attribute__((ext_vector_type(4)));
typedef float vf2 __attribute__((ext_vector_type(2)));

__device__ __forceinline__ float softplus_f(float x) {
    return (x > 20.0f) ? x : log1pf(expf(x));
}

// v9: ONE barrier in the whole kernel. Entire W (Ww+Wn = 128 KiB) staged once
// into dynamic LDS (CDNA4 allows 160 KiB/workgroup); 256 blocks x 1024 thr
// (1 block/CU, 16 waves = 4/SIMD). After the single stage each wave runs 4
// token-groups with ZERO barriers and ZERO W re-staging -> no vmcnt(0)
// drains re-exposing load latency (v7 drained 8x/wave), no sched pins
// (v8's sched_barrier defeated the scheduler, m141 redux). h: dist-1
// register prefetch, compiler-scheduled. LDS layout + read algebra = v7's
// harness-verified both-sides XOR swizzle; butterfly + epilogue verbatim.
__global__ __launch_bounds__(1024, 4)
void noisy_topk_router(const float* __restrict__ h,
                       const float* __restrict__ Ww,
                       const float* __restrict__ bw,
                       const float* __restrict__ Wn,
                       const float* __restrict__ bn,
                       const float* __restrict__ eps,
                       float* __restrict__ out_sparse,
                       float* __restrict__ out_ix,
                       float* __restrict__ out_full)
{
    extern __shared__ vf4 sW4[];     // 8192 vf4 = 128 KiB: all 8 supers

    const int tid  = threadIdx.x;
    const int lane = tid & 63;
    const int wave = tid >> 6;
    const int role = lane & 1;
    const int s7   = lane & 7;

    // ---- one-time W stage (8 vf4/thread), v7-verified per-super mapping ----
    // super S, slot s = S*1024 + k*256 + tt  (tt = tid&255) holds
    // W[wm=(tt>>3)&1][rowgrp k*16+(tt>>4)][wfi=(tt&7)^((tt>>4)&7)]
    {
        const int tt  = tid & 255;
        const int wm  = (tt >> 3) & 1;
        const int wfi = (tt & 7) ^ ((tt >> 4) & 7);
        const float* wsrc = (wm ? Wn : Ww) + (tt >> 4) * 32 + wfi * 4;
#pragma unroll
        for (int it = 0; it < 2; ++it) {
            const int S = (tid >> 8) + it * 4;
#pragma unroll
            for (int k = 0; k < 4; ++k) {
                vf4 v = *(const vf4*)(wsrc + (size_t)S * 2048 + k * 512);
                sW4[S * 1024 + k * 256 + tt] = v;
            }
        }
    }
    __syncthreads();                 // the ONLY barrier

    // ---- per-wave token groups: 8 consecutive tokens, 2 per group ----
#pragma unroll 1
    for (int g = 0; g < GROUPS; ++g) {
        const int t0 = blockIdx.x * (WAVES * TT * GROUPS)
                     + wave * (TT * GROUPS) + g * TT;
        const float* hbase = h + (size_t)t0 * D_DIM + 4 * lane;

        // p2[t*8 + m*4 + e] = partials for outputs (m,2e)/(m,2e+1), token t0+t
        vf2 p2[TT * 8];
#pragma unroll
        for (int i = 0; i < TT * 8; ++i) p2[i] = vf2{0.0f, 0.0f};

        vf4 hbuf[2][TT];
#pragma unroll
        for (int t = 0; t < TT; ++t)
            hbuf[0][t] = *(const vf4*)(hbase + (size_t)t * D_DIM);

#pragma unroll
        for (int S = 0; S < NS; ++S) {
            const int cur = S & 1;
            if (S + 1 < NS) {        // dist-1 h prefetch; no barrier -> stays in flight
#pragma unroll
                for (int t = 0; t < TT; ++t)
                    hbuf[cur ^ 1][t] =
                        *(const vf4*)(hbase + (size_t)t * D_DIM + (S + 1) * SR);
            }

            const int Lb = S * 1024 + lane * 16;
#pragma unroll
            for (int r = 0; r < 4; ++r) {
#pragma unroll
                for (int m = 0; m < 2; ++m) {
                    const vf4 w0 = sW4[Lb + ((m * 8 + r * 2 + 0) ^ s7)];
                    const vf4 w1 = sW4[Lb + ((m * 8 + r * 2 + 1) ^ s7)];
                    const vf2 w0lo = {w0[0], w0[1]}, w0hi = {w0[2], w0[3]};
                    const vf2 w1lo = {w1[0], w1[1]}, w1hi = {w1[2], w1[3]};
#pragma unroll
                    for (int t = 0; t < TT; ++t) {
                        const float x = hbuf[cur][t][r];
                        const vf2 xx = {x, x};
                        p2[t*8 + m*4 + 0] = __builtin_elementwise_fma(xx, w0lo, p2[t*8 + m*4 + 0]);
                        p2[t*8 + m*4 + 1] = __builtin_elementwise_fma(xx, w0hi, p2[t*8 + m*4 + 1]);
                        p2[t*8 + m*4 + 2] = __builtin_elementwise_fma(xx, w1lo, p2[t*8 + m*4 + 2]);
                        p2[t*8 + m*4 + 3] = __builtin_elementwise_fma(xx, w1hi, p2[t*8 + m*4 + 3]);
                    }
                }
            }
        }

        // ---- 5-step compacting butterfly (32 values) + cross-half add ----
        // (v7-verified) lane L ends with value (L&31): t=(L>>4)&1, o=(L>>1)&7,
        // m=L&1; lanes 32-63 mirror lanes 0-31.
        float q[32];
#pragma unroll
        for (int j = 0; j < 32; ++j) {
            const int t = j >> 4, m = j & 1, e = (j >> 2) & 3, el = (j >> 1) & 1;
            q[j] = p2[t*8 + m*4 + e][el];
        }
#pragma unroll
        for (int s = 0; s < 5; ++s) {
            const int mm = 1 << s;
            const bool hi = (lane & mm) != 0;
            const int n = 32 >> (s + 1);
#pragma unroll
            for (int j = 0; j < n; ++j) {
                float a  = q[2 * j];
                float b  = q[2 * j + 1];
                float ta = __shfl_xor(a, mm, 64);
                float tb = __shfl_xor(b, mm, 64);
                q[j] = hi ? (b + tb) : (a + ta);
            }
        }
        const float r0 = q[0] + __shfl_xor(q[0], 32, 64);

        // ---- epilogue (v7-verified): lane L<32 -> token t0+((L>>4)&1),
        // expert (L>>1)&7, matrix L&1 ----
        const int  o         = (lane >> 1) & 7;
        const bool noiseLane = (role != 0);
        const int  tok       = t0 + ((lane >> 4) & 1);
        const float bias     = noiseLane ? bn[o] : bw[o];

        const float val = r0 + bias;
        const float sp  = softplus_f(val);
        const float spN = __shfl_xor(sp, 1, 64);
        const float ev  = eps[(size_t)tok * NEXP + o];
        const float noisy = val + ev * spN;

        float v0 = noisy; int i0 = o;
#pragma unroll
        for (int m = 2; m <= 8; m <<= 1) {
            float ov = __shfl_xor(v0, m, 64);
            int   oi = __shfl_xor(i0, m, 64);
            bool take = (ov > v0) || (ov == v0 && oi < i0);
            v0 = take ? ov : v0;
            i0 = take ? oi : i0;
        }
        float v1 = (o == i0) ? -INFINITY : noisy; int i1 = o;
#pragma unroll
        for (int m = 2; m <= 8; m <<= 1) {
            float ov = __shfl_xor(v1, m, 64);
            int   oi = __shfl_xor(i1, m, 64);
            bool take = (ov > v1) || (ov == v1 && oi < i1);
            v1 = take ? ov : v1;
            i1 = take ? oi : i1;
        }
        const float ex = expf(noisy - v0);
        float ssum = ex;
#pragma unroll
        for (int m = 2; m <= 8; m <<= 1) ssum += __shfl_xor(ssum, m, 64);
        const float fullv = ex / ssum;
        const float dd  = expf(v1 - v0);
        const float den = 1.0f + dd;
        const float sparsev = (o == i0) ? (1.0f / den)
                            : (o == i1) ? (dd / den) : 0.0f;

        if (!noiseLane && lane < 32) {
            out_sparse[(size_t)tok * NEXP + o] = sparsev;
            out_full  [(size_t)tok * NEXP + o] = fullv;
            if (o == 0) {
                out_ix[(size_t)tok * 2]     = (float)i0;
                out_ix[(size_t)tok * 2 + 1] = (float)i1;
            }
        }
    }
}

extern "C" void kernel_launch(void* const* d_in, const int* in_sizes, int n_in,
                              void* d_out, int out_size, void* d_ws, size_t ws_size,
                              hipStream_t stream) {
    const float* h   = (const float*)d_in[0];
    const float* Ww  = (const float*)d_in[1];
    const float* bw  = (const float*)d_in[2];
    const float* Wn  = (const float*)d_in[3];
    const float* bn  = (const float*)d_in[4];
    const float* eps = (const float*)d_in[5];
    // d_in[6] = top_k (always 2 for this problem)

    float* out_sparse = (float*)d_out;                         // [T, 8]
    float* out_ix     = out_sparse + (size_t)NTOK * NEXP;      // [T, 2] (as float)
    float* out_full   = out_ix + (size_t)NTOK * 2;             // [T, 8]

    static bool attr_done = false;
    if (!attr_done) {
        hipFuncSetAttribute((const void*)noisy_topk_router,
                            hipFuncAttributeMaxDynamicSharedMemorySize,
                            131072);
        attr_done = true;
    }
    noisy_topk_router<<<NBLK, BLKT, 131072, stream>>>(h, Ww, bw, Wn, bn, eps,
                                                      out_sparse, out_ix, out_full);
}